// Round 9
// baseline (186.079 us; speedup 1.0000x reference)
//
#include <hip/hip_runtime.h>

typedef __bf16 bf16;
typedef __attribute__((ext_vector_type(8))) bf16 bf16x8;
typedef __attribute__((ext_vector_type(4))) float f32x4;

// async global->LDS (LDS dest is wave-uniform base + lane*16)
#define GLDS16(g, l) __builtin_amdgcn_global_load_lds( \
    (const __attribute__((address_space(1))) void*)(g), \
    (__attribute__((address_space(3))) void*)(l), 16, 0, 0)

// log2(e)/sqrt(128): folded into q at the QKV epilogue so softmax uses exp2 directly
#define QSCALE 0.12751744f

static __device__ __forceinline__ f32x4 MFMA(bf16x8 a, bf16x8 b, f32x4 c) {
    return __builtin_amdgcn_mfma_f32_16x16x32_bf16(a, b, c, 0, 0, 0);
}

// ---------------------------------------------------------------- convert f32->bf16
__global__ __launch_bounds__(256) void convert_kernel(
    const float* __restrict__ x, const float* __restrict__ wq,
    const float* __restrict__ wk, const float* __restrict__ wv,
    const float* __restrict__ wp,
    bf16* __restrict__ xb, bf16* __restrict__ wqkvb, bf16* __restrict__ wpb)
{
    int bid = blockIdx.x;
    const float* src; bf16* dst; int base;
    if (bid < 4096)      { src = x;  dst = xb;              base = bid * 2048; }
    else if (bid < 4608) { src = wq; dst = wqkvb;           base = (bid - 4096) * 2048; }
    else if (bid < 5120) { src = wk; dst = wqkvb + 1048576; base = (bid - 4608) * 2048; }
    else if (bid < 5632) { src = wv; dst = wqkvb + 2097152; base = (bid - 5120) * 2048; }
    else                 { src = wp; dst = wpb;             base = (bid - 5632) * 2048; }
    int i = base + threadIdx.x * 8;
    const f32x4* s4 = (const f32x4*)(src + i);
    f32x4 a = s4[0], c = s4[1];
    bf16x8 v;
    #pragma unroll
    for (int e = 0; e < 4; ++e) { v[e] = (bf16)a[e]; v[e + 4] = (bf16)c[e]; }
    *(bf16x8*)(dst + i) = v;
}

// ---------------------------------------------------------------- 128^2 BK=32 GEMM
// v4: T4 counted-vmcnt pipeline. 3 LDS buffers (48 KiB -> 3 blocks/CU), depth-2
// prefetch: at iter t issue stage(t+2); end-of-iter = s_waitcnt vmcnt(4)
// (tile t+1 resident, t+2's 4 loads STAY IN FLIGHT across the barrier) + raw
// s_barrier. Never vmcnt(0) mid-loop -- this removes the per-iter load-latency
// drain that __syncthreads() (vmcnt 0) forced in R7/R8 (all stuck ~21% MfmaUtil).
// Hazard: buf(t+2) == buf(t-1); its reads completed (consumed by MFMA) before
// iter t-1's barrier, and the write is issued after that barrier -> safe.
// Paired-row swizzled LDS layout (R8, verified 0 conflicts) unchanged.
// MODE 0: QKV epilogue (q scaled, k, v transposed per head); MODE 1: f32+bias.
template <int MODE, int NTN>
__global__ __launch_bounds__(256, 3) void gemm2(
    const bf16* __restrict__ A, const bf16* __restrict__ B,
    const float* __restrict__ bias0, const float* __restrict__ bias1,
    const float* __restrict__ bias2,
    bf16* __restrict__ q_out, bf16* __restrict__ k_out, bf16* __restrict__ vt_out,
    float* __restrict__ f_out)
{
    constexpr int K = 1024;
    constexpr int NT = K / 32;        // 32 K-tiles
    constexpr int NWG = 64 * NTN;
    const int tid = threadIdx.x;
    const int lane = tid & 63;
    const int wid = tid >> 6;
    const int wr = wid >> 1, wc = wid & 1;
    const int l15 = lane & 15, l4 = lane >> 4;

    // bijective XCD chunk swizzle (NWG % 8 == 0)
    const int g = blockIdx.x;
    const int lin = (g & 7) * (NWG / 8) + (g >> 3);
    const int m0 = (lin / NTN) * 128, n0 = (lin % NTN) * 128;

    __shared__ __align__(16) bf16 lds[3][2][4096];  // [buf][A,B][64 lines x 64 elems]

    // staging: thread -> (line = half*32 + tid>>3, phys slot = tid&7);
    // logical q = slot ^ (line&7) -> row = 2*line + (q>>2), kchunk = q&3
    const int ln0 = tid >> 3, pc = tid & 7;
    auto stage = [&](int buf, int t) {
        #pragma unroll
        for (int half = 0; half < 2; ++half) {
            int line = half * 32 + ln0;
            int q = pc ^ (line & 7);
            int row = 2 * line + (q >> 2);
            int c = q & 3;
            GLDS16(A + (size_t)(m0 + row) * K + t * 32 + c * 8,
                   &lds[buf][0][half * 2048 + tid * 8]);
        }
        #pragma unroll
        for (int half = 0; half < 2; ++half) {
            int line = half * 32 + ln0;
            int q = pc ^ (line & 7);
            int row = 2 * line + (q >> 2);
            int c = q & 3;
            GLDS16(B + (size_t)(n0 + row) * K + t * 32 + c * 8,
                   &lds[buf][1][half * 2048 + tid * 8]);
        }
    };

    // frag read: row = base + f*16 + l15, kchunk = l4
    //   line = base/2 + f*8 + (l15>>1); phys = ((l15&1)*4 + l4) ^ ((l15>>1)&7)
    const int physc = (((l15 & 1) * 4 + l4) ^ ((l15 >> 1) & 7)) * 16;
    const int aoff = (wr * 32 + (l15 >> 1)) * 128 + physc;
    const int boff = (wc * 32 + (l15 >> 1)) * 128 + physc;
    #define RA(buf, f) (*(const bf16x8*)((const char*)lds[buf][0] + aoff + (f) * 1024))
    #define RB(buf, j) (*(const bf16x8*)((const char*)lds[buf][1] + boff + (j) * 1024))

    f32x4 acc[4][4];
    #pragma unroll
    for (int f = 0; f < 4; ++f)
        #pragma unroll
        for (int j = 0; j < 4; ++j)
            #pragma unroll
            for (int e = 0; e < 4; ++e) acc[f][j][e] = 0.f;

    // prologue: tiles 0 and 1 staged; vmcnt(4) -> tile 0 resident, tile 1 in flight
    stage(0, 0);
    stage(1, 1);
    asm volatile("s_waitcnt vmcnt(4)" ::: "memory");
    __builtin_amdgcn_sched_barrier(0);
    __builtin_amdgcn_s_barrier();
    __builtin_amdgcn_sched_barrier(0);

    for (int t = 0; t < NT; ++t) {
        const int buf = t % 3;
        if (t + 2 < NT) stage((t + 2) % 3, t + 2);   // depth-2 prefetch
        bf16x8 af[4], bfr[4];
        #pragma unroll
        for (int f = 0; f < 4; ++f) af[f] = RA(buf, f);
        #pragma unroll
        for (int j = 0; j < 4; ++j) bfr[j] = RB(buf, j);
        __builtin_amdgcn_s_setprio(1);
        #pragma unroll
        for (int f = 0; f < 4; ++f)
            #pragma unroll
            for (int j = 0; j < 4; ++j)
                acc[f][j] = MFMA(af[f], bfr[j], acc[f][j]);
        __builtin_amdgcn_s_setprio(0);
        // counted wait: tile t+1 resident, t+2's 4 loads remain in flight
        if (t + 2 < NT) asm volatile("s_waitcnt vmcnt(4) lgkmcnt(0)" ::: "memory");
        else            asm volatile("s_waitcnt vmcnt(0) lgkmcnt(0)" ::: "memory");
        __builtin_amdgcn_sched_barrier(0);
        __builtin_amdgcn_s_barrier();
        __builtin_amdgcn_sched_barrier(0);
    }
    #undef RA
    #undef RB

    // epilogue: C/D layout col = lane&15, row = (lane>>4)*4 + reg  [m89-verified]
    #pragma unroll
    for (int f = 0; f < 4; ++f) {
        #pragma unroll
        for (int j = 0; j < 4; ++j) {
            #pragma unroll
            for (int r = 0; r < 4; ++r) {
                int m = m0 + wr * 64 + f * 16 + l4 * 4 + r;
                int n = n0 + wc * 64 + j * 16 + l15;
                float v = acc[f][j][r];
                if (MODE == 0) {
                    if (n0 < 1024) {
                        q_out[m * 1024 + n] = (bf16)((v + bias0[n]) * QSCALE);
                    } else if (n0 < 2048) {
                        int nn = n - 1024;
                        k_out[m * 1024 + nn] = (bf16)(v + bias1[nn]);
                    } else {
                        int nn = n - 2048;
                        int hl = nn >> 7, d = nn & 127;
                        int bb = m >> 10, tt = m & 1023;
                        vt_out[((bb * 8 + hl) * 128 + d) * 1024 + tt] = (bf16)(v + bias2[nn]);
                    }
                } else {
                    f_out[m * 1024 + n] = v + bias0[n];
                }
            }
        }
    }
}

// ---------------------------------------------------------------- flash attention v3
// grid: 1024 = B(8)*H(8)*(T/64); 4 waves/block, each wave owns 16 q-rows.
// un-subtracted softmax (p = exp2(s), l reduced once in epilogue);
// K/V double-buffer, stage-first, ONE barrier per iter. LDS 72 KiB.
__global__ __launch_bounds__(256, 2) void attn_kernel(
    const bf16* __restrict__ qb, const bf16* __restrict__ kb,
    const bf16* __restrict__ vtb, const int* __restrict__ mask,
    bf16* __restrict__ yb)
{
    const int tid = threadIdx.x;
    const int lane = tid & 63;
    const int wid = tid >> 6;
    const int g = blockIdx.x;
    const int orig = (g & 7) * 128 + (g >> 3);
    const int bh = orig >> 4;
    const int qt = orig & 15;
    const int b = bh >> 3;
    const int h = bh & 7;
    const int m0 = b * 1024 + qt * 64;

    __shared__ __align__(16) char smem[73728];
    auto stageKV = [&](int bufKV, int kt) {
        char* Kb = smem + bufKV * 16384;
        char* Vb = smem + 32768 + bufKV * 16384;
        #pragma unroll
        for (int n = 0; n < 4; ++n)
            GLDS16(kb + (b * 1024 + kt + n * 16 + (tid >> 4)) * 1024 + h * 128 +
                       (((tid & 15) ^ ((tid >> 4) & 7)) * 8),
                   Kb + n * 4096 + tid * 16);
        #pragma unroll
        for (int n = 0; n < 4; ++n)
            GLDS16(vtb + (bh * 128 + n * 32 + (tid >> 3)) * 1024 + kt +
                       (((tid & 7) ^ ((tid >> 3) & 7)) * 8),
                   Vb + n * 4096 + tid * 16);
    };

    bf16x8 qf[4];
    #pragma unroll
    for (int kc = 0; kc < 4; ++kc)
        qf[kc] = *(const bf16x8*)(qb + (m0 + wid * 16 + (lane & 15)) * 1024 +
                                  h * 128 + kc * 32 + (lane >> 4) * 8);

    f32x4 o[8];
    #pragma unroll
    for (int jd = 0; jd < 8; ++jd)
        #pragma unroll
        for (int e = 0; e < 4; ++e) o[jd][e] = 0.f;
    float l_run[4] = {0.f, 0.f, 0.f, 0.f};

    stageKV(0, 0);
    __syncthreads();

    for (int t = 0; t < 16; ++t) {
        const int buf = t & 1;
        const int kt = t * 64;
        if (t + 1 < 16) stageKV(buf ^ 1, kt + 64);

        int mv[4];
        #pragma unroll
        for (int j = 0; j < 4; ++j)
            mv[j] = mask[b * 1024 + kt + j * 16 + (lane & 15)];

        const char* Ks = smem + buf * 16384;
        const char* Vs = smem + 32768 + buf * 16384;

        f32x4 s[4];
        #pragma unroll
        for (int j = 0; j < 4; ++j)
            #pragma unroll
            for (int e = 0; e < 4; ++e) s[j][e] = 0.f;
        #pragma unroll
        for (int kc = 0; kc < 4; ++kc) {
            bf16x8 kf[4];
            #pragma unroll
            for (int j = 0; j < 4; ++j)
                kf[j] = *(const bf16x8*)(Ks +
                    (j * 16 + (lane & 15)) * 256 +
                    (((kc * 4 + (lane >> 4)) ^ (lane & 7)) * 16));
            #pragma unroll
            for (int j = 0; j < 4; ++j)
                s[j] = __builtin_amdgcn_mfma_f32_16x16x32_bf16(qf[kc], kf[j], s[j], 0, 0, 0);
        }

        #pragma unroll
        for (int j = 0; j < 4; ++j) {
            if (mv[j] == 0) {
                #pragma unroll
                for (int e = 0; e < 4; ++e) s[j][e] = -1e30f;
            }
            #pragma unroll
            for (int r = 0; r < 4; ++r) {
                float p = __builtin_amdgcn_exp2f(s[j][r]);
                s[j][r] = p;
                l_run[r] += p;
            }
        }

        #pragma unroll
        for (int j = 0; j < 4; ++j)
            #pragma unroll
            for (int r = 0; r < 4; ++r) {
                int row = (lane >> 4) * 4 + r;
                int col = j * 16 + (lane & 15);
                *(bf16*)(smem + 65536 + wid * 2048 + row * 128 +
                         (((col >> 3) ^ (row & 7)) * 16) + (col & 7) * 2) = (bf16)s[j][r];
            }

        #pragma unroll
        for (int k2 = 0; k2 < 2; ++k2) {
            bf16x8 pa = *(const bf16x8*)(smem + 65536 + wid * 2048 +
                (lane & 15) * 128 + (((k2 * 4 + (lane >> 4)) ^ (lane & 7)) * 16));
            #pragma unroll
            for (int jd = 0; jd < 8; ++jd) {
                bf16x8 vf = *(const bf16x8*)(Vs +
                    (jd * 16 + (lane & 15)) * 128 +
                    (((k2 * 4 + (lane >> 4)) ^ (lane & 7)) * 16));
                o[jd] = __builtin_amdgcn_mfma_f32_16x16x32_bf16(pa, vf, o[jd], 0, 0, 0);
            }
        }
        __syncthreads();
    }

    #pragma unroll
    for (int off = 8; off >= 1; off >>= 1)
        #pragma unroll
        for (int r = 0; r < 4; ++r) l_run[r] += __shfl_xor(l_run[r], off);
    float inv[4];
    #pragma unroll
    for (int r = 0; r < 4; ++r) inv[r] = 1.0f / fmaxf(l_run[r], 1e-30f);
    #pragma unroll
    for (int jd = 0; jd < 8; ++jd)
        #pragma unroll
        for (int r = 0; r < 4; ++r)
            yb[(m0 + wid * 16 + (lane >> 4) * 4 + r) * 1024 +
               h * 128 + jd * 16 + (lane & 15)] = (bf16)(o[jd][r] * inv[r]);
}

// ---------------------------------------------------------------- launch
extern "C" void kernel_launch(void* const* d_in, const int* in_sizes, int n_in,
                              void* d_out, int out_size, void* d_ws, size_t ws_size,
                              hipStream_t stream)
{
    (void)in_sizes; (void)n_in; (void)out_size; (void)ws_size;
    const float* x  = (const float*)d_in[0];
    const int* mask = (const int*)d_in[1];
    const float* Wq = (const float*)d_in[2];
    const float* bq = (const float*)d_in[3];
    const float* Wk = (const float*)d_in[4];
    const float* bk = (const float*)d_in[5];
    const float* Wv = (const float*)d_in[6];
    const float* bv = (const float*)d_in[7];
    const float* Wp = (const float*)d_in[8];
    const float* bp = (const float*)d_in[9];
    float* out = (float*)d_out;

    char* ws = (char*)d_ws;
    bf16* xb    = (bf16*)(ws);                      // 16 MB  x bf16 (8192 x 1024)
    bf16* wqkvb = (bf16*)(ws + (16u << 20));        //  6 MB  [Wq;Wk;Wv]
    bf16* wpb   = (bf16*)(ws + (22u << 20));        //  2 MB  Wp
    bf16* qbuf  = (bf16*)(ws + (24u << 20));        // 16 MB  q (scaled)
    bf16* kbuf  = (bf16*)(ws + (40u << 20));        // 16 MB  k
    bf16* vtb   = (bf16*)(ws + (56u << 20));        // 16 MB  v^T per (b,h)
    bf16* ybuf  = (bf16*)(ws + (72u << 20));        // 16 MB  attention out

    convert_kernel<<<6144, 256, 0, stream>>>(x, Wq, Wk, Wv, Wp, xb, wqkvb, wpb);
    gemm2<0, 24><<<1536, 256, 0, stream>>>(xb, wqkvb, bq, bk, bv,
                                           qbuf, kbuf, vtb, nullptr);
    attn_kernel<<<1024, 256, 0, stream>>>(qbuf, kbuf, vtb, mask, ybuf);
    gemm2<1, 8><<<512, 256, 0, stream>>>(ybuf, wpb, bp, nullptr, nullptr,
                                         nullptr, nullptr, nullptr, out);
}

// Round 10
// 172.669 us; speedup vs baseline: 1.0777x; 1.0777x over previous
//
#include <hip/hip_runtime.h>

typedef __bf16 bf16;
typedef __attribute__((ext_vector_type(8))) bf16 bf16x8;
typedef __attribute__((ext_vector_type(4))) float f32x4;

// async global->LDS (LDS dest is wave-uniform base + lane*16)
#define GLDS16(g, l) __builtin_amdgcn_global_load_lds( \
    (const __attribute__((address_space(1))) void*)(g), \
    (__attribute__((address_space(3))) void*)(l), 16, 0, 0)

// log2(e)/sqrt(128): folded into q at the QKV epilogue so softmax uses exp2 directly
#define QSCALE 0.12751744f

static __device__ __forceinline__ f32x4 MFMA(bf16x8 a, bf16x8 b, f32x4 c) {
    return __builtin_amdgcn_mfma_f32_16x16x32_bf16(a, b, c, 0, 0, 0);
}

// ---------------------------------------------------------------- convert f32->bf16
__global__ __launch_bounds__(256) void convert_kernel(
    const float* __restrict__ x, const float* __restrict__ wq,
    const float* __restrict__ wk, const float* __restrict__ wv,
    const float* __restrict__ wp,
    bf16* __restrict__ xb, bf16* __restrict__ wqkvb, bf16* __restrict__ wpb)
{
    int bid = blockIdx.x;
    const float* src; bf16* dst; int base;
    if (bid < 4096)      { src = x;  dst = xb;              base = bid * 2048; }
    else if (bid < 4608) { src = wq; dst = wqkvb;           base = (bid - 4096) * 2048; }
    else if (bid < 5120) { src = wk; dst = wqkvb + 1048576; base = (bid - 4608) * 2048; }
    else if (bid < 5632) { src = wv; dst = wqkvb + 2097152; base = (bid - 5120) * 2048; }
    else                 { src = wp; dst = wpb;             base = (bid - 5632) * 2048; }
    int i = base + threadIdx.x * 8;
    const f32x4* s4 = (const f32x4*)(src + i);
    f32x4 a = s4[0], c = s4[1];
    bf16x8 v;
    #pragma unroll
    for (int e = 0; e < 4; ++e) { v[e] = (bf16)a[e]; v[e + 4] = (bf16)c[e]; }
    *(bf16x8*)(dst + i) = v;
}

// ---------------------------------------------------------------- 128^2 BK=64 GEMM
// R7 config (measured best: 94 us QKV). BM=BN=128, BK=64, 4 waves (2x2),
// per-wave C = 64x64. LDS 64 KiB -> 2 blocks/CU. Stage-first, ONE barrier/iter.
// Chunk-swizzle (chunk ^= row&7) on global source + ds_read (0 conflicts).
// MODE 0: QKV epilogue (q scaled, k, v transposed per head); MODE 1: f32+bias.
template <int MODE, int NTN>
__global__ __launch_bounds__(256, 2) void gemm2(
    const bf16* __restrict__ A, const bf16* __restrict__ B,
    const float* __restrict__ bias0, const float* __restrict__ bias1,
    const float* __restrict__ bias2,
    bf16* __restrict__ q_out, bf16* __restrict__ k_out, bf16* __restrict__ vt_out,
    float* __restrict__ f_out)
{
    constexpr int K = 1024;
    constexpr int NT = K / 64;        // 16 K-tiles
    constexpr int NWG = 64 * NTN;
    const int tid = threadIdx.x;
    const int lane = tid & 63;
    const int wid = tid >> 6;
    const int wr = wid >> 1, wc = wid & 1;
    const int l15 = lane & 15, l4 = lane >> 4, l7 = lane & 7;

    // bijective XCD chunk swizzle (NWG % 8 == 0)
    const int g = blockIdx.x;
    const int lin = (g & 7) * (NWG / 8) + (g >> 3);
    const int m0 = (lin / NTN) * 128, n0 = (lin % NTN) * 128;

    __shared__ __align__(16) bf16 lds[2][2][8192];  // [buf][A,B][128 x 64]

    const int rr = tid >> 3, pc = tid & 7;
    auto stage = [&](int buf, int t) {
        #pragma unroll
        for (int c = 0; c < 4; ++c) {
            int row = c * 32 + rr;
            int lc = pc ^ (row & 7);
            GLDS16(A + (size_t)(m0 + row) * K + t * 64 + lc * 8,
                   &lds[buf][0][c * 2048 + tid * 8]);
        }
        #pragma unroll
        for (int c = 0; c < 4; ++c) {
            int row = c * 32 + rr;
            int lc = pc ^ (row & 7);
            GLDS16(B + (size_t)(n0 + row) * K + t * 64 + lc * 8,
                   &lds[buf][1][c * 2048 + tid * 8]);
        }
    };

    const int arow = wr * 64 + l15;
    const int brow = wc * 64 + l15;
    #define RA(buf, f, kk) (*(const bf16x8*)((const char*)lds[buf][0] + \
        (arow + (f) * 16) * 128 + ((((kk) * 4 + l4) ^ l7) * 16)))
    #define RB(buf, j, kk) (*(const bf16x8*)((const char*)lds[buf][1] + \
        (brow + (j) * 16) * 128 + ((((kk) * 4 + l4) ^ l7) * 16)))

    f32x4 acc[4][4];
    #pragma unroll
    for (int f = 0; f < 4; ++f)
        #pragma unroll
        for (int j = 0; j < 4; ++j)
            #pragma unroll
            for (int e = 0; e < 4; ++e) acc[f][j][e] = 0.f;

    stage(0, 0);
    __syncthreads();

    for (int t = 0; t < NT; ++t) {
        const int buf = t & 1;
        if (t + 1 < NT) stage(buf ^ 1, t + 1);   // issue next-tile loads FIRST
        bf16x8 af[4][2], bfr[4][2];
        #pragma unroll
        for (int f = 0; f < 4; ++f) { af[f][0] = RA(buf, f, 0); af[f][1] = RA(buf, f, 1); }
        #pragma unroll
        for (int j = 0; j < 4; ++j) { bfr[j][0] = RB(buf, j, 0); bfr[j][1] = RB(buf, j, 1); }
        __builtin_amdgcn_s_setprio(1);
        #pragma unroll
        for (int f = 0; f < 4; ++f)
            #pragma unroll
            for (int j = 0; j < 4; ++j) {
                acc[f][j] = MFMA(af[f][0], bfr[j][0], acc[f][j]);
                acc[f][j] = MFMA(af[f][1], bfr[j][1], acc[f][j]);
            }
        __builtin_amdgcn_s_setprio(0);
        __syncthreads();   // drains vmcnt (stage had the whole phase to land)
    }
    #undef RA
    #undef RB

    // epilogue: C/D layout col = lane&15, row = (lane>>4)*4 + reg  [m89-verified]
    #pragma unroll
    for (int f = 0; f < 4; ++f) {
        #pragma unroll
        for (int j = 0; j < 4; ++j) {
            #pragma unroll
            for (int r = 0; r < 4; ++r) {
                int m = m0 + wr * 64 + f * 16 + l4 * 4 + r;
                int n = n0 + wc * 64 + j * 16 + l15;
                float v = acc[f][j][r];
                if (MODE == 0) {
                    if (n0 < 1024) {
                        q_out[m * 1024 + n] = (bf16)((v + bias0[n]) * QSCALE);
                    } else if (n0 < 2048) {
                        int nn = n - 1024;
                        k_out[m * 1024 + nn] = (bf16)(v + bias1[nn]);
                    } else {
                        int nn = n - 2048;
                        int hl = nn >> 7, d = nn & 127;
                        int bb = m >> 10, tt = m & 1023;
                        vt_out[((bb * 8 + hl) * 128 + d) * 1024 + tt] = (bf16)(v + bias2[nn]);
                    }
                } else {
                    f_out[m * 1024 + n] = v + bias0[n];
                }
            }
        }
    }
}

// ---------------------------------------------------------------- flash attention v4
// grid: 512 = B(8)*H(8)*(T/128); 4 waves/block, each wave owns 32 q-rows.
// v4: QBLK=128 -> each K/V LDS ingest feeds 64 MFMA instead of 32 (bytes/MFMA
// 1.06 -> 0.56 KB; attn is LDS-read-BW dominated like the GEMM). 2 blocks/CU
// (LDS 80 KiB). Un-subtracted softmax + dbuf single-barrier (R7), + setprio.
__global__ __launch_bounds__(256, 2) void attn_kernel(
    const bf16* __restrict__ qb, const bf16* __restrict__ kb,
    const bf16* __restrict__ vtb, const int* __restrict__ mask,
    bf16* __restrict__ yb)
{
    const int tid = threadIdx.x;
    const int lane = tid & 63;
    const int wid = tid >> 6;
    const int g = blockIdx.x;
    const int orig = (g & 7) * 64 + (g >> 3);   // bijective XCD swizzle (512 = 8*64)
    const int bh = orig >> 3;
    const int qt = orig & 7;
    const int b = bh >> 3;
    const int h = bh & 7;
    const int m0 = b * 1024 + qt * 128;
    const int l15 = lane & 15, l4 = lane >> 4;

    __shared__ __align__(16) char smem[81920];
    // K buf: smem + buf*16384          [64 t'][128 d] swizzled
    // V buf: smem + 32768 + buf*16384  [128 d][64 t'] swizzled (V^T)
    // P:     smem + 65536 + wid*4096   per-wave [32][64] swizzled

    auto stageKV = [&](int bufKV, int kt) {
        char* Kb = smem + bufKV * 16384;
        char* Vb = smem + 32768 + bufKV * 16384;
        #pragma unroll
        for (int n = 0; n < 4; ++n)
            GLDS16(kb + (b * 1024 + kt + n * 16 + (tid >> 4)) * 1024 + h * 128 +
                       (((tid & 15) ^ ((tid >> 4) & 7)) * 8),
                   Kb + n * 4096 + tid * 16);
        #pragma unroll
        for (int n = 0; n < 4; ++n)
            GLDS16(vtb + (bh * 128 + n * 32 + (tid >> 3)) * 1024 + kt +
                       (((tid & 7) ^ ((tid >> 3) & 7)) * 8),
                   Vb + n * 4096 + tid * 16);
    };

    // Q fragments: 32 rows per wave (one-time global read, L2-cached)
    bf16x8 qf[2][4];
    #pragma unroll
    for (int i = 0; i < 2; ++i)
        #pragma unroll
        for (int kc = 0; kc < 4; ++kc)
            qf[i][kc] = *(const bf16x8*)(qb +
                (m0 + wid * 32 + i * 16 + l15) * 1024 + h * 128 + kc * 32 + l4 * 8);

    f32x4 o[2][8];
    #pragma unroll
    for (int i = 0; i < 2; ++i)
        #pragma unroll
        for (int jd = 0; jd < 8; ++jd)
            #pragma unroll
            for (int e = 0; e < 4; ++e) o[i][jd][e] = 0.f;
    float l_run[2][4];
    #pragma unroll
    for (int i = 0; i < 2; ++i)
        #pragma unroll
        for (int r = 0; r < 4; ++r) l_run[i][r] = 0.f;

    stageKV(0, 0);
    __syncthreads();

    for (int t = 0; t < 16; ++t) {
        const int buf = t & 1;
        const int kt = t * 64;
        if (t + 1 < 16) stageKV(buf ^ 1, kt + 64);   // issue next K/V FIRST

        int mv[4];
        #pragma unroll
        for (int j = 0; j < 4; ++j)
            mv[j] = mask[b * 1024 + kt + j * 16 + l15];

        const char* Ks = smem + buf * 16384;
        const char* Vs = smem + 32768 + buf * 16384;

        // S = Q K^T  (32 q-rows x 64 t' per wave); kf shared across both i
        f32x4 s[2][4];
        #pragma unroll
        for (int i = 0; i < 2; ++i)
            #pragma unroll
            for (int j = 0; j < 4; ++j)
                #pragma unroll
                for (int e = 0; e < 4; ++e) s[i][j][e] = 0.f;
        #pragma unroll
        for (int kc = 0; kc < 4; ++kc) {
            bf16x8 kf[4];
            #pragma unroll
            for (int j = 0; j < 4; ++j)
                kf[j] = *(const bf16x8*)(Ks + (j * 16 + l15) * 256 +
                    (((kc * 4 + l4) ^ (lane & 7)) * 16));
            __builtin_amdgcn_s_setprio(1);
            #pragma unroll
            for (int i = 0; i < 2; ++i)
                #pragma unroll
                for (int j = 0; j < 4; ++j)
                    s[i][j] = MFMA(qf[i][kc], kf[j], s[i][j]);
            __builtin_amdgcn_s_setprio(0);
        }

        // un-subtracted softmax: p = exp2(s); per-lane partial row-sums only
        #pragma unroll
        for (int i = 0; i < 2; ++i)
            #pragma unroll
            for (int j = 0; j < 4; ++j) {
                if (mv[j] == 0) {
                    #pragma unroll
                    for (int e = 0; e < 4; ++e) s[i][j][e] = -1e30f;
                }
                #pragma unroll
                for (int r = 0; r < 4; ++r) {
                    float p = __builtin_amdgcn_exp2f(s[i][j][r]);
                    s[i][j][r] = p;
                    l_run[i][r] += p;
                }
            }

        // P -> per-wave LDS [32][64] bf16, swizzled (same-wave write->read)
        #pragma unroll
        for (int i = 0; i < 2; ++i)
            #pragma unroll
            for (int j = 0; j < 4; ++j)
                #pragma unroll
                for (int r = 0; r < 4; ++r) {
                    int row = i * 16 + l4 * 4 + r;
                    int col = j * 16 + l15;
                    *(bf16*)(smem + 65536 + wid * 4096 + row * 128 +
                             (((col >> 3) ^ (row & 7)) * 16) + (col & 7) * 2) =
                        (bf16)s[i][j][r];
                }

        // O += P V (vf shared across both i halves)
        #pragma unroll
        for (int k2 = 0; k2 < 2; ++k2) {
            bf16x8 pa[2];
            #pragma unroll
            for (int i = 0; i < 2; ++i)
                pa[i] = *(const bf16x8*)(smem + 65536 + wid * 4096 +
                    (i * 16 + l15) * 128 + (((k2 * 4 + l4) ^ (l15 & 7)) * 16));
            __builtin_amdgcn_s_setprio(1);
            #pragma unroll
            for (int jd = 0; jd < 8; ++jd) {
                bf16x8 vf = *(const bf16x8*)(Vs + (jd * 16 + l15) * 128 +
                    (((k2 * 4 + l4) ^ (l15 & 7)) * 16));
                o[0][jd] = MFMA(pa[0], vf, o[0][jd]);
                o[1][jd] = MFMA(pa[1], vf, o[1][jd]);
            }
            __builtin_amdgcn_s_setprio(0);
        }
        __syncthreads();   // drains own stage loads + protects buf reuse
    }

    // epilogue: single cross-lane reduce of l, then normalize and store
    #pragma unroll
    for (int off = 8; off >= 1; off >>= 1)
        #pragma unroll
        for (int i = 0; i < 2; ++i)
            #pragma unroll
            for (int r = 0; r < 4; ++r) l_run[i][r] += __shfl_xor(l_run[i][r], off);
    #pragma unroll
    for (int i = 0; i < 2; ++i) {
        float inv[4];
        #pragma unroll
        for (int r = 0; r < 4; ++r) inv[r] = 1.0f / fmaxf(l_run[i][r], 1e-30f);
        #pragma unroll
        for (int jd = 0; jd < 8; ++jd)
            #pragma unroll
            for (int r = 0; r < 4; ++r)
                yb[(m0 + wid * 32 + i * 16 + l4 * 4 + r) * 1024 +
                   h * 128 + jd * 16 + l15] = (bf16)(o[i][jd][r] * inv[r]);
    }
}

// ---------------------------------------------------------------- launch
extern "C" void kernel_launch(void* const* d_in, const int* in_sizes, int n_in,
                              void* d_out, int out_size, void* d_ws, size_t ws_size,
                              hipStream_t stream)
{
    (void)in_sizes; (void)n_in; (void)out_size; (void)ws_size;
    const float* x  = (const float*)d_in[0];
    const int* mask = (const int*)d_in[1];
    const float* Wq = (const float*)d_in[2];
    const float* bq = (const float*)d_in[3];
    const float* Wk = (const float*)d_in[4];
    const float* bk = (const float*)d_in[5];
    const float* Wv = (const float*)d_in[6];
    const float* bv = (const float*)d_in[7];
    const float* Wp = (const float*)d_in[8];
    const float* bp = (const float*)d_in[9];
    float* out = (float*)d_out;

    char* ws = (char*)d_ws;
    bf16* xb    = (bf16*)(ws);                      // 16 MB  x bf16 (8192 x 1024)
    bf16* wqkvb = (bf16*)(ws + (16u << 20));        //  6 MB  [Wq;Wk;Wv]
    bf16* wpb   = (bf16*)(ws + (22u << 20));        //  2 MB  Wp
    bf16* qbuf  = (bf16*)(ws + (24u << 20));        // 16 MB  q (scaled)
    bf16* kbuf  = (bf16*)(ws + (40u << 20));        // 16 MB  k
    bf16* vtb   = (bf16*)(ws + (56u << 20));        // 16 MB  v^T per (b,h)
    bf16* ybuf  = (bf16*)(ws + (72u << 20));        // 16 MB  attention out

    convert_kernel<<<6144, 256, 0, stream>>>(x, Wq, Wk, Wv, Wp, xb, wqkvb, wpb);
    gemm2<0, 24><<<1536, 256, 0, stream>>>(xb, wqkvb, bq, bk, bv,
                                           qbuf, kbuf, vtb, nullptr);
    attn_kernel<<<512, 256, 0, stream>>>(qbuf, kbuf, vtb, mask, ybuf);
    gemm2<1, 8><<<512, 256, 0, stream>>>(ybuf, wpb, bp, nullptr, nullptr,
                                         nullptr, nullptr, nullptr, out);
}